// Round 1
// baseline (681.647 us; speedup 1.0000x reference)
//
#include <hip/hip_runtime.h>
#include <float.h>
#include <math.h>

#define NUM_T 8192
#define NUM_E 256
#define HID   7168

// ---------------------------------------------------------------------------
// Kernel 1: partial router logits, fp32 VALU GEMM.
// grid = (NUM_T/64, SPLITK), block = 256 threads (4 waves).
// Tile: 64 tokens x 256 experts; per-thread 8 tokens x 8 experts (64 acc).
// LDS k-major tiles (transpose staged through VGPRs; e-major reads would be
// 32-way bank conflicted).
// ---------------------------------------------------------------------------
template <int SPLITK>
__global__ __launch_bounds__(256, 2) void router_gemm(
    const float* __restrict__ X, const float* __restrict__ W,
    float* __restrict__ partial) {
  __shared__ float xs[32][68];   // [k][token], pad 68 keeps float4 alignment
  __shared__ float ws[32][256];  // [k][expert]

  const int tid = threadIdx.x;
  const int t0 = blockIdx.x * 64;
  const int kLen = HID / SPLITK;
  const int kStart = blockIdx.y * kLen;

  const int tg = tid >> 5;  // 0..7  -> tokens t0 + tg*8 .. +7
  const int eg = tid & 31;  // 0..31 -> experts eg*8 .. +7

  float acc[8][8];
#pragma unroll
  for (int i = 0; i < 8; ++i)
#pragma unroll
    for (int j = 0; j < 8; ++j) acc[i][j] = 0.f;

  const int we = tid >> 3;        // 0..31: W row within 32-row group
  const int wk = (tid & 7) << 2;  // 0..28 step 4: W col offset
  const int xt = tid >> 2;        // 0..63: X row
  const int xk = (tid & 3) << 3;  // 0,8,16,24: X col offset

  for (int kc = 0; kc < kLen; kc += 32) {
    const int k0 = kStart + kc;
    // Stage W chunk (256 x 32) transposed -> ws[k][e]; global reads are
    // 128B-contiguous per 8 lanes.
#pragma unroll
    for (int r = 0; r < 8; ++r) {
      const int e = (r << 5) + we;
      const float4 v =
          *reinterpret_cast<const float4*>(W + (size_t)e * HID + k0 + wk);
      ws[wk + 0][e] = v.x;
      ws[wk + 1][e] = v.y;
      ws[wk + 2][e] = v.z;
      ws[wk + 3][e] = v.w;
    }
    // Stage X chunk (64 x 32) transposed -> xs[k][t]
    {
      const float4 v0 = *reinterpret_cast<const float4*>(
          X + (size_t)(t0 + xt) * HID + k0 + xk);
      const float4 v1 = *reinterpret_cast<const float4*>(
          X + (size_t)(t0 + xt) * HID + k0 + xk + 4);
      xs[xk + 0][xt] = v0.x;
      xs[xk + 1][xt] = v0.y;
      xs[xk + 2][xt] = v0.z;
      xs[xk + 3][xt] = v0.w;
      xs[xk + 4][xt] = v1.x;
      xs[xk + 5][xt] = v1.y;
      xs[xk + 6][xt] = v1.z;
      xs[xk + 7][xt] = v1.w;
    }
    __syncthreads();
#pragma unroll
    for (int k = 0; k < 32; ++k) {
      float xv[8], wv[8];
      *reinterpret_cast<float4*>(&xv[0]) =
          *reinterpret_cast<const float4*>(&xs[k][tg * 8]);
      *reinterpret_cast<float4*>(&xv[4]) =
          *reinterpret_cast<const float4*>(&xs[k][tg * 8 + 4]);
      *reinterpret_cast<float4*>(&wv[0]) =
          *reinterpret_cast<const float4*>(&ws[k][eg * 8]);
      *reinterpret_cast<float4*>(&wv[4]) =
          *reinterpret_cast<const float4*>(&ws[k][eg * 8 + 4]);
#pragma unroll
      for (int i = 0; i < 8; ++i)
#pragma unroll
        for (int j = 0; j < 8; ++j) acc[i][j] = fmaf(xv[i], wv[j], acc[i][j]);
    }
    __syncthreads();
  }

  float* out = partial + (size_t)blockIdx.y * NUM_T * NUM_E;
#pragma unroll
  for (int i = 0; i < 8; ++i) {
    const int t = t0 + tg * 8 + i;
#pragma unroll
    for (int j = 0; j < 8; j += 4) {
      float4 v = make_float4(acc[i][j], acc[i][j + 1], acc[i][j + 2],
                             acc[i][j + 3]);
      *reinterpret_cast<float4*>(out + (size_t)t * NUM_E + eg * 8 + j) = v;
    }
  }
}

// ---------------------------------------------------------------------------
// Kernel 2: per-token selection, one wave per token (4 tokens / 256-thr block).
// Lane l owns experts 4l..4l+3 (all within group l/8). Reproduces jax
// lax.top_k tie-break (lower index first) at both group and expert level,
// including the flat-position ordering through group-rank.
// ---------------------------------------------------------------------------
__global__ __launch_bounds__(256) void router_select(
    const float* __restrict__ partial, int splitk,
    const float* __restrict__ bias, float* __restrict__ outIdx,
    float* __restrict__ outW) {
  const int lane = threadIdx.x & 63;
  const int t = blockIdx.x * 4 + (threadIdx.x >> 6);

  // Sum split-k partial logits
  float lg[4] = {0.f, 0.f, 0.f, 0.f};
  for (int s = 0; s < splitk; ++s) {
    const float4 p = *reinterpret_cast<const float4*>(
        partial + ((size_t)s * NUM_T + t) * NUM_E + lane * 4);
    lg[0] += p.x;
    lg[1] += p.y;
    lg[2] += p.z;
    lg[3] += p.w;
  }
  const float4 bv = *reinterpret_cast<const float4*>(bias + lane * 4);

  float sc[4], bs[4];
#pragma unroll
  for (int j = 0; j < 4; ++j) {
    sc[j] = 1.0f / (1.0f + expf(-lg[j]));  // sigmoid score (weights)
  }
  bs[0] = sc[0] + bv.x;
  bs[1] = sc[1] + bv.y;
  bs[2] = sc[2] + bv.z;
  bs[3] = sc[3] + bv.w;  // scores_for_choice

  // Group sums (8 groups of 32 experts = 8 lanes each)
  const int myg = lane >> 3;
  float gsum = bs[0] + bs[1] + bs[2] + bs[3];
#pragma unroll
  for (int d = 1; d < 8; d <<= 1) gsum += __shfl_xor(gsum, d);

  float gsv[8];
#pragma unroll
  for (int g = 0; g < 8; ++g) gsv[g] = __shfl(gsum, g * 8);

  // Top-4 groups, tie -> lower group index; record selection order (rank)
  unsigned selm = 0;
  int myrank = 0;
#pragma unroll
  for (int r = 0; r < 4; ++r) {
    int best = -1;
    float bvv = -FLT_MAX;
#pragma unroll
    for (int g = 0; g < 8; ++g) {
      if (!((selm >> g) & 1u) && gsv[g] > bvv) {
        bvv = gsv[g];
        best = g;
      }
    }
    selm |= 1u << best;
    if (best == myg) myrank = r;
  }
  const bool gsel = ((selm >> myg) & 1u) != 0u;

  float myv[4];
#pragma unroll
  for (int j = 0; j < 4; ++j) myv[j] = gsel ? bs[j] : -FLT_MAX;

  const int ebase = lane << 2;
  const int flatb = myrank * 32 + (lane & 7) * 4;  // jax flat position base

  float chosen_s = 0.f;
  int ex_out = 0;
  float ssum = 0.f;
  for (int r = 0; r < 8; ++r) {
    // local best among this lane's 4 candidates (value desc, flat asc)
    float v = -FLT_MAX;
    int fl = 1 << 30;
    int ex = 0;
    float s = 0.f;
#pragma unroll
    for (int j = 0; j < 4; ++j) {
      const bool better =
          (myv[j] > v) || (myv[j] == v && (flatb + j) < fl);
      if (better) {
        v = myv[j];
        fl = flatb + j;
        ex = ebase + j;
        s = sc[j];
      }
    }
    // wave butterfly argmax
#pragma unroll
    for (int d = 32; d > 0; d >>= 1) {
      const float v2 = __shfl_xor(v, d);
      const int fl2 = __shfl_xor(fl, d);
      const int ex2 = __shfl_xor(ex, d);
      const float s2 = __shfl_xor(s, d);
      if (v2 > v || (v2 == v && fl2 < fl)) {
        v = v2;
        fl = fl2;
        ex = ex2;
        s = s2;
      }
    }
    ssum += s;
    if (lane == r) {
      chosen_s = s;
      ex_out = ex;
    }
    if ((ex >> 2) == lane) myv[ex & 3] = -FLT_MAX;  // consume winner
  }

  if (lane < 8) {
    outIdx[t * 8 + lane] = (float)ex_out;
    outW[t * 8 + lane] = chosen_s / (ssum + 1e-20f) * 2.5f;
  }
}

extern "C" void kernel_launch(void* const* d_in, const int* in_sizes, int n_in,
                              void* d_out, int out_size, void* d_ws,
                              size_t ws_size, hipStream_t stream) {
  const float* X = (const float*)d_in[0];     // [8192, 7168]
  const float* W = (const float*)d_in[1];     // [256, 7168]
  const float* bias = (const float*)d_in[2];  // [256]
  float* partial = (float*)d_ws;

  const size_t slice = (size_t)NUM_T * NUM_E * sizeof(float);  // 8.4 MB
  int S;
  if (ws_size >= 4 * slice)
    S = 4;
  else if (ws_size >= 2 * slice)
    S = 2;
  else
    S = 1;

  dim3 grid(NUM_T / 64, S);
  if (S == 4)
    router_gemm<4><<<grid, 256, 0, stream>>>(X, W, partial);
  else if (S == 2)
    router_gemm<2><<<grid, 256, 0, stream>>>(X, W, partial);
  else
    router_gemm<1><<<grid, 256, 0, stream>>>(X, W, partial);

  float* outIdx = (float*)d_out;           // indices as exact float ints
  float* outW = outIdx + NUM_T * 8;        // weights
  router_select<<<NUM_T / 4, 256, 0, stream>>>(partial, S, bias, outIdx, outW);
}

// Round 3
// 616.670 us; speedup vs baseline: 1.1054x; 1.1054x over previous
//
#include <hip/hip_runtime.h>
#include <float.h>
#include <math.h>

#define NUM_T 8192
#define NUM_E 256
#define HID   7168

// ---------------------------------------------------------------------------
// Kernel 1: partial router logits, fp32 VALU GEMM.
// grid = (NUM_T/64, SPLITK), block = 256 threads (4 waves).
// Tile: 64 tokens x 256 experts; per-thread 8 tokens x 8 experts (64 acc).
// LDS k-major tiles. Bank-conflict design:
//  - ws column XOR-swizzle: element (k,e) lives at ws[k][e ^ (k&28)].
//    Transpose writes: lane writes 4 rows k=wk..wk+3 at fixed col e^wk
//    -> each bank hit exactly 2 lanes/wave (2-way = free on gfx950).
//    Reads at fixed k: float4 at 4*(eg ^ ((k>>2)&7)) -> permutation of the
//    conflict-free consecutive-16B pattern, still 16B aligned.
//  - Thread expert fragment = {4eg..4eg+3} and {128+4eg..+3} (split halves)
//    so read addresses are consecutive 16B across lanes.
//  - xs reads are wave broadcasts (free).
// ---------------------------------------------------------------------------
template <int SPLITK>
__global__ __launch_bounds__(256, 2) void router_gemm(
    const float* __restrict__ X, const float* __restrict__ W,
    float* __restrict__ partial) {
  __shared__ float xs[32][68];   // [k][token], pad 68 keeps float4 alignment
  __shared__ float ws[32][256];  // [k][expert-swizzled]

  const int tid = threadIdx.x;
  const int t0 = blockIdx.x * 64;
  const int kLen = HID / SPLITK;
  const int kStart = blockIdx.y * kLen;

  const int tg = tid >> 5;  // 0..7  -> tokens t0 + tg*8 .. +7
  const int eg = tid & 31;  // 0..31 -> experts 4eg..+3 and 128+4eg..+3

  // Per-lane swizzled read column (floats) for q = (k>>2)&7
  int wcol[8];
#pragma unroll
  for (int q = 0; q < 8; ++q) wcol[q] = 4 * (eg ^ q);

  float acc[8][8];
#pragma unroll
  for (int i = 0; i < 8; ++i)
#pragma unroll
    for (int j = 0; j < 8; ++j) acc[i][j] = 0.f;

  const int we = tid >> 3;        // 0..31: W row within 32-row group
  const int wk = (tid & 7) << 2;  // 0..28 step 4: W col offset
  const int xt = tid >> 2;        // 0..63: X row
  const int xk = (tid & 3) << 3;  // 0,8,16,24: X col offset

  for (int kc = 0; kc < kLen; kc += 32) {
    const int k0 = kStart + kc;
    // Stage W chunk (256 x 32) transposed+swizzled -> ws[k][e ^ (k&28)]
#pragma unroll
    for (int r = 0; r < 8; ++r) {
      const int e = (r << 5) + we;
      const float4 v =
          *reinterpret_cast<const float4*>(W + (size_t)e * HID + k0 + wk);
      const int pc = e ^ wk;  // (wk+j)&28 == wk for j<4
      ws[wk + 0][pc] = v.x;
      ws[wk + 1][pc] = v.y;
      ws[wk + 2][pc] = v.z;
      ws[wk + 3][pc] = v.w;
    }
    // Stage X chunk (64 x 32) transposed -> xs[k][t]
    {
      const float4 v0 = *reinterpret_cast<const float4*>(
          X + (size_t)(t0 + xt) * HID + k0 + xk);
      const float4 v1 = *reinterpret_cast<const float4*>(
          X + (size_t)(t0 + xt) * HID + k0 + xk + 4);
      xs[xk + 0][xt] = v0.x;
      xs[xk + 1][xt] = v0.y;
      xs[xk + 2][xt] = v0.z;
      xs[xk + 3][xt] = v0.w;
      xs[xk + 4][xt] = v1.x;
      xs[xk + 5][xt] = v1.y;
      xs[xk + 6][xt] = v1.z;
      xs[xk + 7][xt] = v1.w;
    }
    __syncthreads();
#pragma unroll
    for (int k = 0; k < 32; ++k) {
      const int q = (k >> 2) & 7;
      float xv[8], wv[8];
      *reinterpret_cast<float4*>(&xv[0]) =
          *reinterpret_cast<const float4*>(&xs[k][tg * 8]);
      *reinterpret_cast<float4*>(&xv[4]) =
          *reinterpret_cast<const float4*>(&xs[k][tg * 8 + 4]);
      *reinterpret_cast<float4*>(&wv[0]) =
          *reinterpret_cast<const float4*>(&ws[k][wcol[q]]);
      *reinterpret_cast<float4*>(&wv[4]) =
          *reinterpret_cast<const float4*>(&ws[k][wcol[q] + 128]);
#pragma unroll
      for (int i = 0; i < 8; ++i)
#pragma unroll
        for (int j = 0; j < 8; ++j) acc[i][j] = fmaf(xv[i], wv[j], acc[i][j]);
    }
    __syncthreads();
  }

  float* out = partial + (size_t)blockIdx.y * NUM_T * NUM_E;
#pragma unroll
  for (int i = 0; i < 8; ++i) {
    const int t = t0 + tg * 8 + i;
    {
      float4 v = make_float4(acc[i][0], acc[i][1], acc[i][2], acc[i][3]);
      *reinterpret_cast<float4*>(out + (size_t)t * NUM_E + 4 * eg) = v;
    }
    {
      float4 v = make_float4(acc[i][4], acc[i][5], acc[i][6], acc[i][7]);
      *reinterpret_cast<float4*>(out + (size_t)t * NUM_E + 128 + 4 * eg) = v;
    }
  }
}

// ---------------------------------------------------------------------------
// Kernel 2: per-token selection, one wave per token (4 tokens / 256-thr block).
// Lane l owns experts 4l..4l+3 (all within group l/8). Reproduces jax
// lax.top_k tie-break (lower index first) at both group and expert level,
// including the flat-position ordering through group-rank.
// ---------------------------------------------------------------------------
__global__ __launch_bounds__(256) void router_select(
    const float* __restrict__ partial, int splitk,
    const float* __restrict__ bias, float* __restrict__ outIdx,
    float* __restrict__ outW) {
  const int lane = threadIdx.x & 63;
  const int t = blockIdx.x * 4 + (threadIdx.x >> 6);

  // Sum split-k partial logits
  float lg[4] = {0.f, 0.f, 0.f, 0.f};
  for (int s = 0; s < splitk; ++s) {
    const float4 p = *reinterpret_cast<const float4*>(
        partial + ((size_t)s * NUM_T + t) * NUM_E + lane * 4);
    lg[0] += p.x;
    lg[1] += p.y;
    lg[2] += p.z;
    lg[3] += p.w;
  }
  const float4 bv = *reinterpret_cast<const float4*>(bias + lane * 4);

  float sc[4], bs[4];
#pragma unroll
  for (int j = 0; j < 4; ++j) {
    sc[j] = 1.0f / (1.0f + expf(-lg[j]));  // sigmoid score (weights)
  }
  bs[0] = sc[0] + bv.x;
  bs[1] = sc[1] + bv.y;
  bs[2] = sc[2] + bv.z;
  bs[3] = sc[3] + bv.w;  // scores_for_choice

  // Group sums (8 groups of 32 experts = 8 lanes each)
  const int myg = lane >> 3;
  float gsum = bs[0] + bs[1] + bs[2] + bs[3];
#pragma unroll
  for (int d = 1; d < 8; d <<= 1) gsum += __shfl_xor(gsum, d);

  float gsv[8];
#pragma unroll
  for (int g = 0; g < 8; ++g) gsv[g] = __shfl(gsum, g * 8);

  // Top-4 groups, tie -> lower group index; record selection order (rank)
  unsigned selm = 0;
  int myrank = 0;
#pragma unroll
  for (int r = 0; r < 4; ++r) {
    int best = -1;
    float bvv = -FLT_MAX;
#pragma unroll
    for (int g = 0; g < 8; ++g) {
      if (!((selm >> g) & 1u) && gsv[g] > bvv) {
        bvv = gsv[g];
        best = g;
      }
    }
    selm |= 1u << best;
    if (best == myg) myrank = r;
  }
  const bool gsel = ((selm >> myg) & 1u) != 0u;

  float myv[4];
#pragma unroll
  for (int j = 0; j < 4; ++j) myv[j] = gsel ? bs[j] : -FLT_MAX;

  const int ebase = lane << 2;
  const int flatb = myrank * 32 + (lane & 7) * 4;  // jax flat position base

  float chosen_s = 0.f;
  int ex_out = 0;
  float ssum = 0.f;
  for (int r = 0; r < 8; ++r) {
    // local best among this lane's 4 candidates (value desc, flat asc)
    float v = -FLT_MAX;
    int fl = 1 << 30;
    int ex = 0;
    float s = 0.f;
#pragma unroll
    for (int j = 0; j < 4; ++j) {
      const bool better =
          (myv[j] > v) || (myv[j] == v && (flatb + j) < fl);
      if (better) {
        v = myv[j];
        fl = flatb + j;
        ex = ebase + j;
        s = sc[j];
      }
    }
    // wave butterfly argmax
#pragma unroll
    for (int d = 32; d > 0; d >>= 1) {
      const float v2 = __shfl_xor(v, d);
      const int fl2 = __shfl_xor(fl, d);
      const int ex2 = __shfl_xor(ex, d);
      const float s2 = __shfl_xor(s, d);
      if (v2 > v || (v2 == v && fl2 < fl)) {
        v = v2;
        fl = fl2;
        ex = ex2;
        s = s2;
      }
    }
    ssum += s;
    if (lane == r) {
      chosen_s = s;
      ex_out = ex;
    }
    if ((ex >> 2) == lane) myv[ex & 3] = -FLT_MAX;  // consume winner
  }

  if (lane < 8) {
    outIdx[t * 8 + lane] = (float)ex_out;
    outW[t * 8 + lane] = chosen_s / (ssum + 1e-20f) * 2.5f;
  }
}

extern "C" void kernel_launch(void* const* d_in, const int* in_sizes, int n_in,
                              void* d_out, int out_size, void* d_ws,
                              size_t ws_size, hipStream_t stream) {
  const float* X = (const float*)d_in[0];     // [8192, 7168]
  const float* W = (const float*)d_in[1];     // [256, 7168]
  const float* bias = (const float*)d_in[2];  // [256]
  float* partial = (float*)d_ws;

  const size_t slice = (size_t)NUM_T * NUM_E * sizeof(float);  // 8.4 MB
  int S;
  if (ws_size >= 4 * slice)
    S = 4;
  else if (ws_size >= 2 * slice)
    S = 2;
  else
    S = 1;

  dim3 grid(NUM_T / 64, S);
  if (S == 4)
    router_gemm<4><<<grid, 256, 0, stream>>>(X, W, partial);
  else if (S == 2)
    router_gemm<2><<<grid, 256, 0, stream>>>(X, W, partial);
  else
    router_gemm<1><<<grid, 256, 0, stream>>>(X, W, partial);

  float* outIdx = (float*)d_out;           // indices as exact float ints
  float* outW = outIdx + NUM_T * 8;        // weights
  router_select<<<NUM_T / 4, 256, 0, stream>>>(partial, S, bias, outIdx, outW);
}